// Round 2
// baseline (605.989 us; speedup 1.0000x reference)
//
#include <hip/hip_runtime.h>
#include <hip/hip_bf16.h>
#include <cstdint>
#include <cstddef>

using bf16 = __hip_bfloat16;
typedef __bf16 bf16x8 __attribute__((ext_vector_type(8)));
typedef float f32x4 __attribute__((ext_vector_type(4)));
typedef float f32x16 __attribute__((ext_vector_type(16)));

// ---- constants for this problem ----
#define BB 16
#define TT 1024
#define DD 1024
#define EE 64
#define MREAL 16368   // (TT-1)*BB
#define MPAD  16384
#define NCHUNK 16
#define CHUNK 64

__device__ __forceinline__ void gload_lds16(const void* g, void* l) {
  __builtin_amdgcn_global_load_lds((const __attribute__((address_space(1))) void*)g,
                                   (__attribute__((address_space(3))) void*)l,
                                   16, 0, 0);
}

__device__ __forceinline__ float sigmoidf_(float x) {
  return 1.0f / (1.0f + __expf(-x));
}

// ---------------- fp32 -> bf16 weight conversion (8 elems/thread, 16B store) ----
__global__ void f2b(const float* __restrict__ src, bf16* __restrict__ dst, int n) {
  int i = (blockIdx.x * blockDim.x + threadIdx.x) * 8;
  if (i < n) {
    float4 v0 = *reinterpret_cast<const float4*>(src + i);
    float4 v1 = *reinterpret_cast<const float4*>(src + i + 4);
    alignas(16) bf16 tmp[8];
    tmp[0] = __float2bfloat16(v0.x); tmp[1] = __float2bfloat16(v0.y);
    tmp[2] = __float2bfloat16(v0.z); tmp[3] = __float2bfloat16(v0.w);
    tmp[4] = __float2bfloat16(v1.x); tmp[5] = __float2bfloat16(v1.y);
    tmp[6] = __float2bfloat16(v1.z); tmp[7] = __float2bfloat16(v1.w);
    *reinterpret_cast<float4*>(dst + i) = *reinterpret_cast<const float4*>(tmp);
  }
}

// ---------------- EMA pass 1: chunk-local endpoints ----------------
__global__ void ema_ends(const float* __restrict__ seq, const float* __restrict__ beta_raw,
                         float* __restrict__ ends) {
  int tid = blockIdx.x * blockDim.x + threadIdx.x;
  int d = tid & (DD - 1);
  int b = (tid >> 10) & (BB - 1);
  int c = tid >> 14;
  float beta = sigmoidf_(beta_raw[d]);
  int t0 = c * CHUNK;
  int len = min(CHUNK, (TT - 1) - t0);
  const float* p = seq + (size_t)b * TT * DD + (size_t)t0 * DD + d;
  float h = 0.0f;
#pragma unroll 8
  for (int j = 0; j < len; ++j) h = fmaf(beta, h, p[(size_t)j * DD]);
  ends[tid] = h;
}

// ---------------- EMA pass 2: carry combine (per chain) ----------------
__global__ void ema_carry(const float* __restrict__ ends, const float* __restrict__ beta_raw,
                          float* __restrict__ carry) {
  int tid = blockIdx.x * blockDim.x + threadIdx.x;
  int d = tid & (DD - 1);
  float beta = sigmoidf_(beta_raw[d]);
  float bl = beta;
  bl *= bl; bl *= bl; bl *= bl; bl *= bl; bl *= bl; bl *= bl;  // beta^64
  float run = 0.0f;
#pragma unroll
  for (int c = 0; c < NCHUNK; ++c) {
    carry[c * (BB * DD) + tid] = run;
    run = ends[c * (BB * DD) + tid] + bl * run;
  }
}

// ---------------- EMA pass 3: recompute + write A = [x | h] in bf16 ----------------
__global__ void ema_write(const float* __restrict__ seq, const float* __restrict__ beta_raw,
                          const float* __restrict__ carry, bf16* __restrict__ A) {
  int tid = blockIdx.x * blockDim.x + threadIdx.x;
  int d = tid & (DD - 1);
  int b = (tid >> 10) & (BB - 1);
  int c = tid >> 14;
  float beta = sigmoidf_(beta_raw[d]);
  int t0 = c * CHUNK;
  int len = min(CHUNK, (TT - 1) - t0);
  const float* p = seq + (size_t)b * TT * DD + (size_t)t0 * DD + d;
  float h = carry[tid];
#pragma unroll 4
  for (int j = 0; j < len; ++j) {
    float x = p[(size_t)j * DD];
    h = fmaf(beta, h, x);
    size_t m = (size_t)(t0 + j) * BB + b;
    A[m * (2 * DD) + d]      = __float2bfloat16(x);
    A[m * (2 * DD) + DD + d] = __float2bfloat16(h);
  }
}

// =====================================================================
// 256x256 8-phase GEMM, 32x32x16 MFMA: C = act(A @ B^T + bias)
// A: (M, K) bf16 row-major, B: (N, K) bf16 row-major. BK=64.
// 512 threads = 8 waves in 2(M)x4(N); per-wave 128x64 out as 4Mf x 2Nf frags
// of 32x32 (acc[4][2] f32x16 = 128 AGPR). LDS 128 KiB: [dbuf][A|B][half 128x64].
// MFMA floor: 8 waves x 32 mfma x 8.07cyc = 2066 cyc/K-tile/CU (vs 2483 for
// 16x16x32 at the 2075 TF rate -> -17%).
// Swizzle: physical 16B-colgroup = logical ^ (row&7); realized by pre-swizzled
// per-lane GLOBAL source (gload_lds dest linear). Verified 0 conflicts (R1).
//
// Per K-tile q (dbuf d=q&1), 4 phases, quad order (Mf01,N0)(Mf01,N1)(Mf23,N1)
// (Mf23,N0); reads 12/4/8/0 ds_read_b128. One half-tile staged per phase:
// A(q+1) halves at sub0/1 -> dbuf d^1; B(q+2) halves at sub2/3 -> dbuf d.
// Counted s_waitcnt vmcnt(4) ONCE per tile at sub3, placed BEFORE the barrier
// (each wave vouches for its own staged loads; barrier makes it collective).
// No interior lgkmcnt pins: compiler emits fine-grained lgkmcnt between
// ds_read and MFMA (near-optimal per m97 asm evidence); barriers + setprio
// keep the 8-wave lockstep.
// =====================================================================

#define RD_A2(d, m0)                                                         \
  _Pragma("unroll")                                                          \
  for (int mf = 0; mf < 2; ++mf)                                             \
    _Pragma("unroll")                                                        \
    for (int ks = 0; ks < 4; ++ks)                                           \
      a[mf][ks] = *reinterpret_cast<const bf16x8*>(                          \
          &lds[(d) * 32768 + aB0 + ((m0) + mf) * 2048 + pgs[ks]]);

#define RD_B4(d, nf, breg)                                                   \
  _Pragma("unroll")                                                          \
  for (int ks = 0; ks < 4; ++ks)                                             \
    breg[ks] = *reinterpret_cast<const bf16x8*>(                             \
        &lds[(d) * 32768 + bO[nf] + pgs[ks]]);

#define STAGE_A(d, h, kq)                                                    \
  {                                                                          \
    _Pragma("unroll")                                                        \
    for (int t = 0; t < 2; ++t)                                              \
      gload_lds16(gA + ((size_t)((h) * 128 + t * 8) * K + (kq) * 64),        \
                  &lds[(d) * 32768 + (h) * 8192 + stbase + t * 512]);        \
  }

#define STAGE_B(d, h, kq)                                                    \
  {                                                                          \
    _Pragma("unroll")                                                        \
    for (int t = 0; t < 2; ++t)                                              \
      gload_lds16(gB + ((size_t)((h) * 128 + t * 8) * K + (kq) * 64),        \
                  &lds[(d) * 32768 + 16384 + (h) * 8192 + stbase + t * 512]); \
  }

// one phase: barrier | setprio(1) | 8 MFMA (2 chains of 4) | setprio(0) | barrier
#define PH_MFMA(m0, breg, nf)                                                \
  __builtin_amdgcn_s_barrier();                                              \
  __builtin_amdgcn_s_setprio(1);                                             \
  _Pragma("unroll")                                                          \
  for (int ks = 0; ks < 4; ++ks) {                                           \
    acc[(m0)][nf] = __builtin_amdgcn_mfma_f32_32x32x16_bf16(                 \
        a[0][ks], breg[ks], acc[(m0)][nf], 0, 0, 0);                         \
    acc[(m0) + 1][nf] = __builtin_amdgcn_mfma_f32_32x32x16_bf16(             \
        a[1][ks], breg[ks], acc[(m0) + 1][nf], 0, 0, 0);                     \
  }                                                                          \
  __builtin_amdgcn_s_setprio(0);                                             \
  __builtin_amdgcn_s_barrier();

#define KTILE(d)                                                             \
  {                                                                          \
    const int kA = (q + 1 < NT) ? (q + 1) : (NT - 1);                        \
    const int kB = (q + 2 < NT) ? (q + 2) : (NT - 1);                        \
    /* sub0: (Mf01, N0) */                                                   \
    RD_A2(d, 0);                                                             \
    RD_B4(d, 0, b0);                                                         \
    STAGE_A((d) ^ 1, 0, kA);                                                 \
    PH_MFMA(0, b0, 0);                                                       \
    /* sub1: (Mf01, N1) */                                                   \
    RD_B4(d, 1, b1);                                                         \
    STAGE_A((d) ^ 1, 1, kA);                                                 \
    PH_MFMA(0, b1, 1);                                                       \
    /* sub2: (Mf23, N1) */                                                   \
    RD_A2(d, 2);                                                             \
    asm volatile("" ::: "memory"); /* keep B reads above same-dbuf stage */  \
    STAGE_B((d), 0, kB);                                                     \
    PH_MFMA(2, b1, 1);                                                       \
    /* sub3: (Mf23, N0) */                                                   \
    asm volatile("" ::: "memory");                                           \
    STAGE_B((d), 1, kB);                                                     \
    asm volatile("s_waitcnt vmcnt(4)" ::: "memory");                         \
    PH_MFMA(2, b0, 0);                                                       \
    ++q;                                                                     \
  }

template <bool RELU, bool DUAL_OUT>
__global__ __launch_bounds__(512, 2)
void gemm8(const bf16* __restrict__ A, const bf16* __restrict__ B,
           const float* __restrict__ bias, bf16* __restrict__ outb,
           float* __restrict__ outf, int N, int K) {
  __shared__ bf16 lds[65536];  // 128 KiB
  const int tid  = threadIdx.x;
  const int wave = tid >> 6;
  const int lane = tid & 63;
  const int wm = wave >> 2;  // 0..1 (M half of block)
  const int wn = wave & 3;   // 0..3 (N quarter)

  // XCD-aware bijective swizzle (nwg % 8 == 0 for both launches)
  const int gx   = gridDim.x;
  const int nwg  = gx * gridDim.y;
  const int orig = blockIdx.y * gx + blockIdx.x;
  const int swz  = (orig & 7) * (nwg >> 3) + (orig >> 3);
  const int bm = (swz / gx) * 256;
  const int bn = (swz % gx) * 256;

  // staging: wave w, instr t covers 8 rows (w*16 + t*8 .. +8) x 128B of a
  // half-tile; per-lane global source pre-swizzled: logical cg = (l&7)^(l>>3)
  const int srow = lane >> 3;
  const int scg  = (lane & 7) ^ srow;
  const bf16* gA = A + (size_t)(bm + wave * 16 + srow) * K + scg * 8;
  const bf16* gB = B + (size_t)(bn + wave * 16 + srow) * K + scg * 8;
  const int stbase = wave * 1024;  // (wave*16 rows) * 64 elems

  // ds_read addressing (32x32x16 frags): lane reads row (lane&31) of its
  // frag block, 8 bf16 at logical granule ks*2 + (lane>>5), physical
  // granule = logical ^ (row&7), row&7 == lane&7.
  int pgs[4];
#pragma unroll
  for (int ks = 0; ks < 4; ++ks)
    pgs[ks] = (((ks * 2 + (lane >> 5)) ^ (lane & 7)) * 8);
  const int aB0 = wm * 8192 + (lane & 31) * 64;  // + Mf*2048 per frag
  int bO[2];
#pragma unroll
  for (int nf = 0; nf < 2; ++nf) {
    const int rb = wn * 64 + nf * 32 + (lane & 31);  // B-tile row 0..255
    bO[nf] = 16384 + (rb >> 7) * 8192 + (rb & 127) * 64;
  }

  f32x16 acc[4][2] = {};
  bf16x8 a[2][4], b0[4], b1[4];
  const int NT = K >> 6;
  int q = 0;

  // ---- prologue: A(0), B(0), B(1); land K-tile 0, keep B(1) in flight ----
  STAGE_A(0, 0, 0);
  STAGE_A(0, 1, 0);
  STAGE_B(0, 0, 0);
  STAGE_B(0, 1, 0);
  STAGE_B(1, 0, 1);
  STAGE_B(1, 1, 1);
  asm volatile("s_waitcnt vmcnt(4)" ::: "memory");
  __builtin_amdgcn_s_barrier();

#pragma unroll 1
  for (int it = 0; it < (NT >> 1); ++it) {
    KTILE(0);
    KTILE(1);
  }
  asm volatile("s_waitcnt vmcnt(0)" ::: "memory");  // drain tail garbage stages

  // ---- epilogue: 32x32 C/D layout: col = lane&31,
  // row = (r&3) + 8*(r>>2) + 4*(lane>>5) ----
  float bv[2];
  int   ncol[2];
#pragma unroll
  for (int nf = 0; nf < 2; ++nf) {
    ncol[nf] = bn + wn * 64 + nf * 32 + (lane & 31);
    bv[nf]   = bias[ncol[nf]];
  }
#pragma unroll
  for (int mf = 0; mf < 4; ++mf) {
    const int m0 = bm + wm * 128 + mf * 32 + 4 * (lane >> 5);
#pragma unroll
    for (int nf = 0; nf < 2; ++nf) {
      const int n = ncol[nf];
#pragma unroll
      for (int r = 0; r < 16; ++r) {
        const int m = m0 + (r & 3) + 8 * (r >> 2);
        float v = acc[mf][nf][r] + bv[nf];
        if (RELU) v = fmaxf(v, 0.0f);
        outb[(size_t)m * N + n] = __float2bfloat16(v);
        if (DUAL_OUT) {
          if (m < MREAL) outf[(size_t)m * N + n] = v;
        }
      }
    }
  }
}

// ---------------- router GEMM: logits = (Xhat @ Ww^T + Wb) * pi ----------------
// A: (MPAD, 1024) bf16, B: (64, 1024) bf16. 64x64 tile, 256 threads, 16x16x32.
__global__ __launch_bounds__(256)
void gemm_router(const bf16* __restrict__ A, const bf16* __restrict__ B,
                 const float* __restrict__ Wb, const float* __restrict__ pi,
                 float* __restrict__ out) {
  const int K = DD;
  __shared__ alignas(16) bf16 As[64 * 32];
  __shared__ alignas(16) bf16 Bs[64 * 32];
  const int tid  = threadIdx.x;
  const int wave = tid >> 6;
  const int lane = tid & 63;
  const int bm = blockIdx.x * 64;
  const int srow = wave * 16 + (lane >> 2);
  const int scol = (lane & 3) * 8;
  const bf16* gA = A + (size_t)(bm + srow) * K + scol;
  const bf16* gB = B + (size_t)srow * K + scol;
  bf16* lA = &As[srow * 32 + scol];
  bf16* lB = &Bs[srow * 32 + scol];
  const int lr = lane & 15;
  const int quad = lane >> 4;
  f32x4 acc[4] = {};
  for (int k0 = 0; k0 < K; k0 += 32) {
    __syncthreads();
    gload_lds16(gA + k0, lA);
    gload_lds16(gB + k0, lB);
    __syncthreads();
    bf16x8 af = *reinterpret_cast<const bf16x8*>(&As[(wave * 16 + lr) * 32 + quad * 8]);
#pragma unroll
    for (int j = 0; j < 4; ++j) {
      bf16x8 bf_ = *reinterpret_cast<const bf16x8*>(&Bs[(j * 16 + lr) * 32 + quad * 8]);
      acc[j] = __builtin_amdgcn_mfma_f32_16x16x32_bf16(af, bf_, acc[j], 0, 0, 0);
    }
  }
#pragma unroll
  for (int j = 0; j < 4; ++j) {
    const int e = j * 16 + lr;
    const float wb = Wb[e], pv = pi[e];
#pragma unroll
    for (int r = 0; r < 4; ++r) {
      const int m = bm + wave * 16 + quad * 4 + r;
      if (m < MREAL) out[(size_t)m * EE + e] = (acc[j][r] + wb) * pv;
    }
  }
}

extern "C" void kernel_launch(void* const* d_in, const int* in_sizes, int n_in,
                              void* d_out, int out_size, void* d_ws, size_t ws_size,
                              hipStream_t stream) {
  const float* seq      = (const float*)d_in[0];
  const float* pi       = (const float*)d_in[1];
  const float* beta_raw = (const float*)d_in[2];
  const float* p1_w     = (const float*)d_in[3];
  const float* p1_b     = (const float*)d_in[4];
  const float* p2_w     = (const float*)d_in[5];
  const float* p2_b     = (const float*)d_in[6];
  const float* W_w      = (const float*)d_in[7];
  const float* W_b      = (const float*)d_in[8];

  // workspace layout (bytes); Xhat_bf16 aliases A (A dead after GEMM1)
  constexpr size_t A_off    = 0;
  constexpr size_t A_sz     = (size_t)MPAD * 2 * DD * sizeof(bf16);   //  64 MiB
  constexpr size_t W1_off   = A_off + A_sz;
  constexpr size_t W1_sz    = (size_t)4 * DD * 2 * DD * sizeof(bf16); //  16 MiB
  constexpr size_t HID_off  = W1_off + W1_sz;
  constexpr size_t HID_sz   = (size_t)MPAD * 4 * DD * sizeof(bf16);   // 128 MiB
  constexpr size_t W2_off   = HID_off + HID_sz;
  constexpr size_t W2_sz    = (size_t)DD * 4 * DD * sizeof(bf16);     //   8 MiB
  constexpr size_t W3_off   = W2_off + W2_sz;
  constexpr size_t W3_sz    = (size_t)EE * DD * sizeof(bf16);
  constexpr size_t ENDS_off = W3_off + W3_sz;
  constexpr size_t ENDS_sz  = (size_t)NCHUNK * BB * DD * sizeof(float);
  constexpr size_t CARRY_off = ENDS_off + ENDS_sz;

  char* ws = (char*)d_ws;
  bf16*  Abuf = (bf16*)(ws + A_off);
  bf16*  W1   = (bf16*)(ws + W1_off);
  bf16*  HID  = (bf16*)(ws + HID_off);
  bf16*  W2   = (bf16*)(ws + W2_off);
  bf16*  W3   = (bf16*)(ws + W3_off);
  float* ENDS = (float*)(ws + ENDS_off);
  float* CARRY = (float*)(ws + CARRY_off);
  bf16*  XH   = (bf16*)(ws + A_off);  // alias of A

  float* out_logits = (float*)d_out;
  float* out_xhat   = out_logits + (size_t)MREAL * EE;

  // 1) weights -> bf16
  f2b<<<(4 * DD * 2 * DD / 8 + 255) / 256, 256, 0, stream>>>(p1_w, W1, 4 * DD * 2 * DD);
  f2b<<<(DD * 4 * DD / 8 + 255) / 256, 256, 0, stream>>>(p2_w, W2, DD * 4 * DD);
  f2b<<<(EE * DD / 8 + 255) / 256, 256, 0, stream>>>(W_w, W3, EE * DD);

  // 2) EMA scan (chunked 3-pass) -> A = [x | h] bf16
  ema_ends<<<NCHUNK * BB * DD / 256, 256, 0, stream>>>(seq, beta_raw, ENDS);
  ema_carry<<<BB * DD / 256, 256, 0, stream>>>(ENDS, beta_raw, CARRY);
  ema_write<<<NCHUNK * BB * DD / 256, 256, 0, stream>>>(seq, beta_raw, CARRY, Abuf);
  (void)hipMemsetAsync(ws + A_off + (size_t)MREAL * 2 * DD * sizeof(bf16), 0,
                       (size_t)(MPAD - MREAL) * 2 * DD * sizeof(bf16), stream);

  // 3) GEMM1: hid = relu(A @ p1_w^T + b1)   (16384 x 4096, K=2048)
  gemm8<true, false><<<dim3(4 * DD / 256, MPAD / 256), 512, 0, stream>>>(
      Abuf, W1, p1_b, HID, nullptr, 4 * DD, 2 * DD);

  // 4) GEMM2: x_hat = hid @ p2_w^T + b2     (16384 x 1024, K=4096) -> f32 out + bf16 ws
  gemm8<false, true><<<dim3(DD / 256, MPAD / 256), 512, 0, stream>>>(
      HID, W2, p2_b, XH, out_xhat, DD, 4 * DD);

  // 5) GEMM3: logits = (x_hat @ W_w^T + W_b) * pi   (16368 x 64, K=1024)
  gemm_router<<<MPAD / 64, 256, 0, stream>>>(XH, W3, W_b, pi, out_logits);
}

// Round 4
// 563.893 us; speedup vs baseline: 1.0747x; 1.0747x over previous
//
#include <hip/hip_runtime.h>
#include <hip/hip_bf16.h>
#include <cstdint>
#include <cstddef>

using bf16 = __hip_bfloat16;
typedef __bf16 bf16x8 __attribute__((ext_vector_type(8)));
typedef float f32x4 __attribute__((ext_vector_type(4)));

// ---- constants for this problem ----
#define BB 16
#define TT 1024
#define DD 1024
#define EE 64
#define MREAL 16368   // (TT-1)*BB
#define MPAD  16384
#define NCHUNK 16
#define CHUNK 64

__device__ __forceinline__ void gload_lds16(const void* g, void* l) {
  __builtin_amdgcn_global_load_lds((const __attribute__((address_space(1))) void*)g,
                                   (__attribute__((address_space(3))) void*)l,
                                   16, 0, 0);
}

__device__ __forceinline__ float sigmoidf_(float x) {
  return 1.0f / (1.0f + __expf(-x));
}

// ---------------- fp32 -> bf16 weight conversion (8 elems/thread, 16B store) ----
__global__ void f2b(const float* __restrict__ src, bf16* __restrict__ dst, int n) {
  int i = (blockIdx.x * blockDim.x + threadIdx.x) * 8;
  if (i < n) {
    float4 v0 = *reinterpret_cast<const float4*>(src + i);
    float4 v1 = *reinterpret_cast<const float4*>(src + i + 4);
    alignas(16) bf16 tmp[8];
    tmp[0] = __float2bfloat16(v0.x); tmp[1] = __float2bfloat16(v0.y);
    tmp[2] = __float2bfloat16(v0.z); tmp[3] = __float2bfloat16(v0.w);
    tmp[4] = __float2bfloat16(v1.x); tmp[5] = __float2bfloat16(v1.y);
    tmp[6] = __float2bfloat16(v1.z); tmp[7] = __float2bfloat16(v1.w);
    *reinterpret_cast<float4*>(dst + i) = *reinterpret_cast<const float4*>(tmp);
  }
}

// ---------------- EMA pass 1: chunk-local endpoints ----------------
__global__ void ema_ends(const float* __restrict__ seq, const float* __restrict__ beta_raw,
                         float* __restrict__ ends) {
  int tid = blockIdx.x * blockDim.x + threadIdx.x;
  int d = tid & (DD - 1);
  int b = (tid >> 10) & (BB - 1);
  int c = tid >> 14;
  float beta = sigmoidf_(beta_raw[d]);
  int t0 = c * CHUNK;
  int len = min(CHUNK, (TT - 1) - t0);
  const float* p = seq + (size_t)b * TT * DD + (size_t)t0 * DD + d;
  float h = 0.0f;
#pragma unroll 8
  for (int j = 0; j < len; ++j) h = fmaf(beta, h, p[(size_t)j * DD]);
  ends[tid] = h;
}

// ---------------- EMA pass 2: carry combine (per chain) ----------------
__global__ void ema_carry(const float* __restrict__ ends, const float* __restrict__ beta_raw,
                          float* __restrict__ carry) {
  int tid = blockIdx.x * blockDim.x + threadIdx.x;
  int d = tid & (DD - 1);
  float beta = sigmoidf_(beta_raw[d]);
  float bl = beta;
  bl *= bl; bl *= bl; bl *= bl; bl *= bl; bl *= bl; bl *= bl;  // beta^64
  float run = 0.0f;
#pragma unroll
  for (int c = 0; c < NCHUNK; ++c) {
    carry[c * (BB * DD) + tid] = run;
    run = ends[c * (BB * DD) + tid] + bl * run;
  }
}

// ---------------- EMA pass 3: recompute + write A = [x | h] in bf16 ----------------
__global__ void ema_write(const float* __restrict__ seq, const float* __restrict__ beta_raw,
                          const float* __restrict__ carry, bf16* __restrict__ A) {
  int tid = blockIdx.x * blockDim.x + threadIdx.x;
  int d = tid & (DD - 1);
  int b = (tid >> 10) & (BB - 1);
  int c = tid >> 14;
  float beta = sigmoidf_(beta_raw[d]);
  int t0 = c * CHUNK;
  int len = min(CHUNK, (TT - 1) - t0);
  const float* p = seq + (size_t)b * TT * DD + (size_t)t0 * DD + d;
  float h = carry[tid];
#pragma unroll 4
  for (int j = 0; j < len; ++j) {
    float x = p[(size_t)j * DD];
    h = fmaf(beta, h, x);
    size_t m = (size_t)(t0 + j) * BB + b;
    A[m * (2 * DD) + d]      = __float2bfloat16(x);
    A[m * (2 * DD) + DD + d] = __float2bfloat16(h);
  }
}

// =====================================================================
// 256x256 8-phase GEMM, 16x16x32 MFMA (R1-verified fragments/swizzle),
// with SHADOW ds_reads: each phase's LDS reads are issued in the MFMA
// shadow of the PREVIOUS phase (after the MFMA cluster, before the closing
// barrier), so the LDS read pipe overlaps the matrix pipe instead of
// strictly alternating with it (R1 measured 1182 cyc/phase = 621 MFMA +
// ~560 serial read window; this targets ~850-900).
//
// A: (M, K) bf16 rm, B: (N, K) bf16 rm. BK=64. 512 thr = 8 waves 2(M)x4(N);
// per-wave 128x64 out, acc[8][4] f32x4. LDS 128 KiB [dbuf][A|B][half 128x64].
// Swizzle: physical 16B-colgroup = logical ^ (row&7), store-side realized by
// pre-swizzled per-lane GLOBAL source. 16x16 read pattern: 0 conflicts (R1);
// the 32x32 pattern is NOT conflict-free under this swizzle (R2: 2.5e7).
//
// Per K-tile q (dbuf d=q&1) 4 phases; N-quadrant order ALTERNATES per tile
// (even: N0,N1,N1,N0 / odd: N1,N0,N0,N1) so shadow loads land >=1 phase
// after the target registers' last use. Shadow read counts: 4/8/4/8.
//
// Staging (2 x gload_lds16 per phase porch): P0/P1 = A(q+1) halves -> d^1,
// P2/P3 = B(q+2) halves -> d. Counted waits, never 0 in-loop:
//   P2 porch: vmcnt(6)  -> vouches B(q+1) before its shadow read at P2
//             (leaves A(q+1) 4 + B(q+2)h0 2 in flight)
//   P3 porch: vmcnt(4)  -> vouches A(q+1) before its shadow read at P3
//             (leaves B(q+2) 4 in flight = steady state)
// Prologue: stage A(0),B(0),B(1) (12 loads), vmcnt(4) lands tile 0, then
// pre-load tile-0 P0 fragments (a03 + b01).
// Race audit (R3): shadow reads may be in flight past the close barrier
// (s_barrier doesn't drain lgkm); next-porch gload_lds writes never overlap
// the preceding shadow-read region (checked all 8 transitions).
// =====================================================================

#define RD_A(d, fb)                                                          \
  _Pragma("unroll")                                                          \
  for (int f = 0; f < 4; ++f)                                                \
    _Pragma("unroll")                                                        \
    for (int s = 0; s < 2; ++s)                                              \
      a[f][s] = *reinterpret_cast<const bf16x8*>(                            \
          &lds[(d) * 32768 + ArdB + ((fb) + f) * 1024 + roff[s]]);

#define RD_B(d, j0)                                                          \
  _Pragma("unroll")                                                          \
  for (int jj = 0; jj < 2; ++jj)                                             \
    _Pragma("unroll")                                                        \
    for (int s = 0; s < 2; ++s)                                              \
      b[(j0) + jj][s] = *reinterpret_cast<const bf16x8*>(                    \
          &lds[(d) * 32768 + BrdB + ((j0) + jj) * 1024 + roff[s]]);

#define STAGE_A(d, h, kq)                                                    \
  {                                                                          \
    _Pragma("unroll")                                                        \
    for (int t = 0; t < 2; ++t)                                              \
      gload_lds16(gA + ((size_t)((h) * 128 + t * 8) * K + (kq) * 64),        \
                  &lds[(d) * 32768 + (h) * 8192 + stbase + t * 512]);        \
  }

#define STAGE_B(d, h, kq)                                                    \
  {                                                                          \
    _Pragma("unroll")                                                        \
    for (int t = 0; t < 2; ++t)                                              \
      gload_lds16(gB + ((size_t)((h) * 128 + t * 8) * K + (kq) * 64),        \
                  &lds[(d) * 32768 + 16384 + (h) * 8192 + stbase + t * 512]); \
  }

#define MFMA_Q(fb, j0)                                                       \
  _Pragma("unroll")                                                          \
  for (int s = 0; s < 2; ++s)                                                \
    _Pragma("unroll")                                                        \
    for (int f = 0; f < 4; ++f)                                              \
      _Pragma("unroll")                                                      \
      for (int j = 0; j < 2; ++j)                                            \
        acc[(fb) + f][(j0) + j] = __builtin_amdgcn_mfma_f32_16x16x32_bf16(   \
            a[f][s], b[(j0) + j][s], acc[(fb) + f][(j0) + j], 0, 0, 0);

#define PH_OPEN()                                                            \
  __builtin_amdgcn_s_barrier();                                              \
  asm volatile("s_waitcnt lgkmcnt(0)" ::: "memory");                         \
  __builtin_amdgcn_sched_barrier(0);                                         \
  __builtin_amdgcn_s_setprio(1);

#define PH_SHDW()                                                            \
  __builtin_amdgcn_s_setprio(0);                                             \
  __builtin_amdgcn_sched_barrier(0);

#define PH_CLOSE()                                                           \
  __builtin_amdgcn_sched_barrier(0);                                         \
  __builtin_amdgcn_s_barrier();

template <bool RELU, bool DUAL_OUT>
__global__ __launch_bounds__(512, 2)
void gemm8(const bf16* __restrict__ A, const bf16* __restrict__ B,
           const float* __restrict__ bias, bf16* __restrict__ outb,
           float* __restrict__ outf, int N, int K) {
  __shared__ bf16 lds[65536];  // 128 KiB
  const int tid  = threadIdx.x;
  const int wave = tid >> 6;
  const int lane = tid & 63;
  const int wm = wave >> 2;  // 0..1 (M half of block)
  const int wn = wave & 3;   // 0..3 (N quarter)

  // XCD-aware bijective swizzle (nwg % 8 == 0 for both launches)
  const int gx   = gridDim.x;
  const int nwg  = gx * gridDim.y;
  const int orig = blockIdx.y * gx + blockIdx.x;
  const int swz  = (orig & 7) * (nwg >> 3) + (orig >> 3);
  const int bm = (swz / gx) * 256;
  const int bn = (swz % gx) * 256;

  // staging: wave w, instr t covers 8 rows (w*16 + t*8 .. +8) x 128 B of a
  // half-tile; per-lane global source pre-swizzled: logical cg = (l&7)^(l>>3)
  const int srow = lane >> 3;
  const int scg  = (lane & 7) ^ srow;
  const bf16* gA = A + (size_t)(bm + wave * 16 + srow) * K + scg * 8;
  const bf16* gB = B + (size_t)(bn + wave * 16 + srow) * K + scg * 8;
  const int stbase = wave * 1024;  // (wave*16 rows) * 64 elems

  // ds_read per-lane offsets (elements): row (l&15), k-granule (s*4+(l>>4)),
  // physical cg = granule ^ (row&7)   [R1-verified: 0 bank conflicts]
  int roff[2];
#pragma unroll
  for (int s = 0; s < 2; ++s)
    roff[s] = (lane & 15) * 64 + (((s * 4 + (lane >> 4)) ^ (lane & 7)) * 8);
  const int ArdB = wm * 8192;                                   // A half = wm
  const int BrdB = 16384 + (wn >> 1) * 8192 + (wn & 1) * 4096;  // B half + 64-row sub

  f32x4 acc[8][4] = {};
  bf16x8 a[4][2], b[4][2];
  const int NT = K >> 6;

  // ---- prologue: A(0), B(0), B(1); land K-tile 0, keep B(1) in flight ----
  STAGE_A(0, 0, 0);
  STAGE_A(0, 1, 0);
  STAGE_B(0, 0, 0);
  STAGE_B(0, 1, 0);
  STAGE_B(1, 0, 1);
  STAGE_B(1, 1, 1);
  asm volatile("s_waitcnt vmcnt(4)" ::: "memory");
  __builtin_amdgcn_s_barrier();
  // pre-load tile-0 P0 fragments: a rows0-3 + b01
  RD_A(0, 0);
  RD_B(0, 0);

  int q = 0;
#pragma unroll 1
  for (int it = 0; it < (NT >> 1); ++it) {
    {  // ---- even tile, d=0: quadrants (0,N0),(0,N1),(4,N1),(4,N0) ----
      const int kA = (q + 1 < NT) ? (q + 1) : (NT - 1);
      const int kB = (q + 2 < NT) ? (q + 2) : (NT - 1);
      // P0
      STAGE_A(1, 0, kA);
      PH_OPEN(); MFMA_Q(0, 0); PH_SHDW(); RD_B(0, 2); PH_CLOSE();
      // P1
      STAGE_A(1, 1, kA);
      PH_OPEN(); MFMA_Q(0, 2); PH_SHDW(); RD_A(0, 4); PH_CLOSE();
      // P2
      STAGE_B(0, 0, kB);
      asm volatile("s_waitcnt vmcnt(6)" ::: "memory");
      PH_OPEN(); MFMA_Q(4, 2); PH_SHDW(); RD_B(1, 2); PH_CLOSE();
      // P3
      STAGE_B(0, 1, kB);
      asm volatile("s_waitcnt vmcnt(4)" ::: "memory");
      PH_OPEN(); MFMA_Q(4, 0); PH_SHDW(); RD_A(1, 0); PH_CLOSE();
      ++q;
    }
    {  // ---- odd tile, d=1: quadrants (0,N1),(0,N0),(4,N0),(4,N1) ----
      const int kA = (q + 1 < NT) ? (q + 1) : (NT - 1);
      const int kB = (q + 2 < NT) ? (q + 2) : (NT - 1);
      // P0
      STAGE_A(0, 0, kA);
      PH_OPEN(); MFMA_Q(0, 2); PH_SHDW(); RD_B(1, 0); PH_CLOSE();
      // P1
      STAGE_A(0, 1, kA);
      PH_OPEN(); MFMA_Q(0, 0); PH_SHDW(); RD_A(1, 4); PH_CLOSE();
      // P2
      STAGE_B(1, 0, kB);
      asm volatile("s_waitcnt vmcnt(6)" ::: "memory");
      PH_OPEN(); MFMA_Q(4, 0); PH_SHDW(); RD_B(0, 0); PH_CLOSE();
      // P3
      STAGE_B(1, 1, kB);
      asm volatile("s_waitcnt vmcnt(4)" ::: "memory");
      PH_OPEN(); MFMA_Q(4, 2); PH_SHDW(); RD_A(0, 0); PH_CLOSE();
      ++q;
    }
  }
  asm volatile("s_waitcnt vmcnt(0)" ::: "memory");  // drain tail garbage stages

  // ---- epilogue: 16x16 C/D layout: n = lane&15, m = (lane>>4)*4 + r ----
  float bv[4];
  int   ncol[4];
#pragma unroll
  for (int j = 0; j < 4; ++j) {
    ncol[j] = bn + wn * 64 + j * 16 + (lane & 15);
    bv[j]   = bias[ncol[j]];
  }
#pragma unroll
  for (int f = 0; f < 8; ++f) {
    const int m0 = bm + wm * 128 + f * 16 + (lane >> 4) * 4;
#pragma unroll
    for (int j = 0; j < 4; ++j) {
      const int n = ncol[j];
#pragma unroll
      for (int r = 0; r < 4; ++r) {
        float v = acc[f][j][r] + bv[j];
        if (RELU) v = fmaxf(v, 0.0f);
        const int m = m0 + r;
        outb[(size_t)m * N + n] = __float2bfloat16(v);
        if (DUAL_OUT) {
          if (m < MREAL) outf[(size_t)m * N + n] = v;
        }
      }
    }
  }
}

// ---------------- router GEMM: logits = (Xhat @ Ww^T + Wb) * pi ----------------
// A: (MPAD, 1024) bf16, B: (64, 1024) bf16. 64x64 tile, 256 threads, 16x16x32.
__global__ __launch_bounds__(256)
void gemm_router(const bf16* __restrict__ A, const bf16* __restrict__ B,
                 const float* __restrict__ Wb, const float* __restrict__ pi,
                 float* __restrict__ out) {
  const int K = DD;
  __shared__ alignas(16) bf16 As[64 * 32];
  __shared__ alignas(16) bf16 Bs[64 * 32];
  const int tid  = threadIdx.x;
  const int wave = tid >> 6;
  const int lane = tid & 63;
  const int bm = blockIdx.x * 64;
  const int srow = wave * 16 + (lane >> 2);
  const int scol = (lane & 3) * 8;
  const bf16* gA = A + (size_t)(bm + srow) * K + scol;
  const bf16* gB = B + (size_t)srow * K + scol;
  bf16* lA = &As[srow * 32 + scol];
  bf16* lB = &Bs[srow * 32 + scol];
  const int lr = lane & 15;
  const int quad = lane >> 4;
  f32x4 acc[4] = {};
  for (int k0 = 0; k0 < K; k0 += 32) {
    __syncthreads();
    gload_lds16(gA + k0, lA);
    gload_lds16(gB + k0, lB);
    __syncthreads();
    bf16x8 af = *reinterpret_cast<const bf16x8*>(&As[(wave * 16 + lr) * 32 + quad * 8]);
#pragma unroll
    for (int j = 0; j < 4; ++j) {
      bf16x8 bf_ = *reinterpret_cast<const bf16x8*>(&Bs[(j * 16 + lr) * 32 + quad * 8]);
      acc[j] = __builtin_amdgcn_mfma_f32_16x16x32_bf16(af, bf_, acc[j], 0, 0, 0);
    }
  }
#pragma unroll
  for (int j = 0; j < 4; ++j) {
    const int e = j * 16 + lr;
    const float wb = Wb[e], pv = pi[e];
#pragma unroll
    for (int r = 0; r < 4; ++r) {
      const int m = bm + wave * 16 + quad * 4 + r;
      if (m < MREAL) out[(size_t)m * EE + e] = (acc[j][r] + wb) * pv;
    }
  }
}

extern "C" void kernel_launch(void* const* d_in, const int* in_sizes, int n_in,
                              void* d_out, int out_size, void* d_ws, size_t ws_size,
                              hipStream_t stream) {
  const float* seq      = (const float*)d_in[0];
  const float* pi       = (const float*)d_in[1];
  const float* beta_raw = (const float*)d_in[2];
  const float* p1_w     = (const float*)d_in[3];
  const float* p1_b     = (const float*)d_in[4];
  const float* p2_w     = (const float*)d_in[5];
  const float* p2_b     = (const float*)d_in[6];
  const float* W_w      = (const float*)d_in[7];
  const float* W_b      = (const float*)d_in[8];

  // workspace layout (bytes); Xhat_bf16 aliases A (A dead after GEMM1)
  constexpr size_t A_off    = 0;
  constexpr size_t A_sz     = (size_t)MPAD * 2 * DD * sizeof(bf16);   //  64 MiB
  constexpr size_t W1_off   = A_off + A_sz;
  constexpr size_t W1_sz    = (size_t)4 * DD * 2 * DD * sizeof(bf16); //  16 MiB
  constexpr size_t HID_off  = W1_off + W1_sz;
  constexpr size_t HID_sz   = (size_t)MPAD * 4 * DD * sizeof(bf16);   // 128 MiB
  constexpr size_t W2_off   = HID_off + HID_sz;
  constexpr size_t W2_sz    = (size_t)DD * 4 * DD * sizeof(bf16);     //   8 MiB
  constexpr size_t W3_off   = W2_off + W2_sz;
  constexpr size_t W3_sz    = (size_t)EE * DD * sizeof(bf16);
  constexpr size_t ENDS_off = W3_off + W3_sz;
  constexpr size_t ENDS_sz  = (size_t)NCHUNK * BB * DD * sizeof(float);
  constexpr size_t CARRY_off = ENDS_off + ENDS_sz;

  char* ws = (char*)d_ws;
  bf16*  Abuf = (bf16*)(ws + A_off);
  bf16*  W1   = (bf16*)(ws + W1_off);
  bf16*  HID  = (bf16*)(ws + HID_off);
  bf16*  W2   = (bf16*)(ws + W2_off);
  bf16*  W3   = (bf16*)(ws + W3_off);
  float* ENDS = (float*)(ws + ENDS_off);
  float* CARRY = (float*)(ws + CARRY_off);
  bf16*  XH   = (bf16*)(ws + A_off);  // alias of A

  float* out_logits = (float*)d_out;
  float* out_xhat   = out_logits + (size_t)MREAL * EE;

  // 1) weights -> bf16
  f2b<<<(4 * DD * 2 * DD / 8 + 255) / 256, 256, 0, stream>>>(p1_w, W1, 4 * DD * 2 * DD);
  f2b<<<(DD * 4 * DD / 8 + 255) / 256, 256, 0, stream>>>(p2_w, W2, DD * 4 * DD);
  f2b<<<(EE * DD / 8 + 255) / 256, 256, 0, stream>>>(W_w, W3, EE * DD);

  // 2) EMA scan (chunked 3-pass) -> A = [x | h] bf16
  ema_ends<<<NCHUNK * BB * DD / 256, 256, 0, stream>>>(seq, beta_raw, ENDS);
  ema_carry<<<BB * DD / 256, 256, 0, stream>>>(ENDS, beta_raw, CARRY);
  ema_write<<<NCHUNK * BB * DD / 256, 256, 0, stream>>>(seq, beta_raw, CARRY, Abuf);
  (void)hipMemsetAsync(ws + A_off + (size_t)MREAL * 2 * DD * sizeof(bf16), 0,
                       (size_t)(MPAD - MREAL) * 2 * DD * sizeof(bf16), stream);

  // 3) GEMM1: hid = relu(A @ p1_w^T + b1)   (16384 x 4096, K=2048)
  gemm8<true, false><<<dim3(4 * DD / 256, MPAD / 256), 512, 0, stream>>>(
      Abuf, W1, p1_b, HID, nullptr, 4 * DD, 2 * DD);

  // 4) GEMM2: x_hat = hid @ p2_w^T + b2     (16384 x 1024, K=4096) -> f32 out + bf16 ws
  gemm8<false, true><<<dim3(DD / 256, MPAD / 256), 512, 0, stream>>>(
      HID, W2, p2_b, XH, out_xhat, DD, 4 * DD);

  // 5) GEMM3: logits = (x_hat @ W_w^T + W_b) * pi   (16368 x 64, K=1024)
  gemm_router<<<MPAD / 64, 256, 0, stream>>>(XH, W3, W_b, pi, out_logits);
}